// Round 2
// baseline (169.565 us; speedup 1.0000x reference)
//
#include <hip/hip_runtime.h>
#include <hip/hip_bf16.h>

// B=64, S=2048, D=256, VOCAB=288. M=131072, T derived host-side.
//
// KEY: out[row] depends only on code = (day%7)*T + (tod%T) -> only 7*T=2016
// distinct output rows.
//   prep_all  : Htab[7T][256] bf16 = relu(W1[day]+W1[7+tod]+b1); W2S swizzle; TE probe
//   otab_gemm : Otab[2048][256] fp32 = Htab @ W2 + b2   (16-block MFMA, ~4us)
//   gather_out: out[row] = Otab[code(TE[row])]          (pure copy, write-roofline)
// Fallback: if ws_size can't hold Otab, run the proven R0 temb_gemm path.
// All stores are PLAIN (no nontemporal): nt stores can be clobbered by dirty
// poison lines the harness's fillBuffer leaves in per-XCD L2s.

typedef __bf16 bf16x4 __attribute__((ext_vector_type(4)));
typedef __bf16 bf16x8 __attribute__((ext_vector_type(8)));
typedef float  f32x4  __attribute__((ext_vector_type(4)));

#define M_TOTAL   131072
#define BM        128            // rows per block in GEMM kernels (4 waves x 32 rows)

// ws layout: [0,128K) W2S | [128K, +7T*512) Htab | flag (R0-compatible offset) | Otab

// ---- prep: Htab + W2S + TE dtype probe (verified R0) -----------------------
__global__ __launch_bounds__(64) void prep_all(const float* __restrict__ W1,
                                               const float* __restrict__ b1,
                                               const float* __restrict__ W2,
                                               __bf16* __restrict__ W2S,
                                               __bf16* __restrict__ Htab,
                                               const int* __restrict__ TE32,
                                               int* __restrict__ flag, int T) {
    const int b = blockIdx.x, lane = threadIdx.x;
    const int nTab = 7 * T;
    if (b < nTab) {
        const float* __restrict__ wa = W1 + (b / T) * 256;
        const float* __restrict__ wb = W1 + (7 + b % T) * 256;
        f32x4 a = *(const f32x4*)(wa + lane * 4);
        f32x4 c = *(const f32x4*)(wb + lane * 4);
        f32x4 d = *(const f32x4*)(b1 + lane * 4);
        bf16x4 h;
#pragma unroll
        for (int j = 0; j < 4; ++j) h[j] = (__bf16)fmaxf(a[j] + c[j] + d[j], 0.0f);
        *(bf16x4*)(Htab + b * 256 + lane * 4) = h;
    } else {
        const int wb = b - nTab;               // 0..63
        // W2S chunk c = (nt*8+ks)*64+l ; elem j -> W2[ks*32+(l>>4)*8+j][nt*16+(l&15)]
#pragma unroll
        for (int q = 0; q < 2; ++q) {
            int c = (wb * 64 + lane) * 2 + q;  // 0..8191
            int l = c & 63, ksnt = c >> 6;
            int ks = ksnt & 7, nt = ksnt >> 3;
            int n  = nt * 16 + (l & 15);
            int k0 = ks * 32 + (l >> 4) * 8;
            bf16x8 w;
#pragma unroll
            for (int j = 0; j < 8; ++j) w[j] = (__bf16)W2[(k0 + j) * 256 + n];
            *(bf16x8*)(W2S + c * 8) = w;
        }
        if (wb == 0) {  // TE dtype probe: int64 => odd int32 words all zero
            int v = 0;
            for (int i = lane; i < 2048; i += 64) v |= TE32[2 * i + 1];
            unsigned long long nz = __ballot(v != 0);
            if (lane == 0) *flag = (nz == 0ull) ? 1 : 0;
        }
    }
}

// ---- Otab GEMM: 2048 padded rows of Htab @ W2 + b2 -> fp32 table -----------
__global__ __launch_bounds__(256, 3) void otab_gemm(
        const __bf16* __restrict__ Htab, // [7T][256] bf16
        const __bf16* __restrict__ W2S,  // fragment-linear bf16 (128 KB)
        const float* __restrict__ b2,    // [256]
        float* __restrict__ Otab, int T) // [otab_rows,256] fp32
{
    __shared__ __bf16 Bs[4 * 8 * 512];   // 32 KB: one group = 4 n-tiles of W2 frags

    const int tid  = threadIdx.x;
    const int wave = tid >> 6;
    const int lane = tid & 63;
    const int m    = lane & 15;
    const int quad = lane >> 4;
    const int rowBase = blockIdx.x * BM + wave * 32;
    const int nTab = 7 * T;

    // h fragments: lane holds h[row=rowBase+t*16+m][k=ks*32+quad*8+j]; row IS the code
    int code[2];
#pragma unroll
    for (int t = 0; t < 2; ++t) {
        int row = rowBase + t * 16 + m;
        code[t] = row < nTab ? row : nTab - 1;   // clamp padded tail (never gathered)
    }
    bf16x8 hfrag[2][8];
#pragma unroll
    for (int t = 0; t < 2; ++t)
#pragma unroll
        for (int ks = 0; ks < 8; ++ks)
            hfrag[t][ks] = *(const bf16x8*)(Htab + code[t] * 256 + ks * 32 + quad * 8);

    const bf16x8* __restrict__ gsrc = (const bf16x8*)W2S + tid;
    bf16x8* __restrict__ ldst = (bf16x8*)Bs + tid;
    const bf16x8* __restrict__ lsrc = (const bf16x8*)Bs;

    bf16x8 stage[8];
#pragma unroll
    for (int q = 0; q < 8; ++q) stage[q] = gsrc[q * 256];        // group 0

    for (int g = 0; g < 4; ++g) {
#pragma unroll
        for (int q = 0; q < 8; ++q) ldst[q * 256] = stage[q];
        __syncthreads();
        if (g < 3) {
#pragma unroll
            for (int q = 0; q < 8; ++q) stage[q] = gsrc[(g + 1) * 2048 + q * 256];
        }
#pragma unroll
        for (int ntl = 0; ntl < 4; ++ntl) {
            const int nt = g * 4 + ntl;
            f32x4 acc0 = {0.f, 0.f, 0.f, 0.f};
            f32x4 acc1 = {0.f, 0.f, 0.f, 0.f};
#pragma unroll
            for (int ks = 0; ks < 8; ++ks) {
                bf16x8 wfrag = lsrc[(ntl * 8 + ks) * 64 + lane];   // A-operand (W2)
                acc0 = __builtin_amdgcn_mfma_f32_16x16x32_bf16(wfrag, hfrag[0][ks], acc0, 0, 0, 0);
                acc1 = __builtin_amdgcn_mfma_f32_16x16x32_bf16(wfrag, hfrag[1][ks], acc1, 0, 0, 0);
            }
            const f32x4 bias = *(const f32x4*)(b2 + nt * 16 + quad * 4);
            f32x4 v0, v1;
#pragma unroll
            for (int r = 0; r < 4; ++r) { v0[r] = acc0[r] + bias[r]; v1[r] = acc1[r] + bias[r]; }
            float* p0 = Otab + (rowBase + m) * 256 + nt * 16 + quad * 4;
            *(f32x4*)p0 = v0;
            *(f32x4*)(p0 + 16 * 256) = v1;
        }
        __syncthreads();
    }
}

// ---- gather: out[row] = Otab[code(TE[row])] --------------------------------
// Block = 256 thr = 4 waves, 64 rows/block. Codes staged in LDS (no readlane).
// Per row: wave does one coalesced 1KB load (L2-hot Otab) + 1KB plain store.
__global__ __launch_bounds__(256) void gather_out(
        const int*   __restrict__ TE32,  // [M,2] int32 or int64 word view
        const float* __restrict__ Otab,  // [otab_rows,256] fp32
        const int*   __restrict__ flag,  // 1 if TE is int64
        float* __restrict__ out, int T)  // [M,256] fp32
{
    __shared__ int codes[64];
    const int tid  = threadIdx.x;
    const int wave = tid >> 6;
    const int lane = tid & 63;
    const int rowBase = blockIdx.x * 64;

    if (tid < 64) {
        const int is64 = *flag;
        const int row = rowBase + tid;
        int d32, t32;
        if (is64) { int4 te = *(const int4*)(TE32 + 4 * row); d32 = te.x; t32 = te.z; }
        else      { int2 te = *(const int2*)(TE32 + 2 * row); d32 = te.x; t32 = te.y; }
        // reference-exact: int32 cast then Python-style mod (non-negative)
        int day = d32 % 7; if (day < 0) day += 7;
        int tod = t32 % T; if (tod < 0) tod += T;
        codes[tid] = day * T + tod;
    }
    __syncthreads();

    const float* src0 = Otab + lane * 4;
    float*       dst0 = out + (size_t)rowBase * 256 + (size_t)wave * 16 * 256 + lane * 4;
#pragma unroll
    for (int r = 0; r < 16; ++r) {
        const int c = codes[wave * 16 + r];          // wave-uniform LDS broadcast
        f32x4 v = *(const f32x4*)(src0 + (size_t)c * 256);
        *(f32x4*)(dst0 + (size_t)r * 256) = v;
    }
}

// ---- fallback main (verbatim proven R0 kernel, 166us) ----------------------
__global__ __launch_bounds__(256, 3) void temb_gemm(
        const int*   __restrict__ TE32,  // [M,2] int32 or int64 word view
        const __bf16* __restrict__ Htab, // [7T][256] bf16
        const __bf16* __restrict__ W2S,  // fragment-linear bf16 (128 KB)
        const float* __restrict__ b2,    // [256]
        const int*   __restrict__ flag,  // 1 if TE is int64
        float* __restrict__ out, int T)  // [M,256] fp32
{
    __shared__ __bf16 Bs[4 * 8 * 512];   // 32 KB

    const int is64 = *flag;              // wave-uniform
    const int tid  = threadIdx.x;
    const int wave = tid >> 6;
    const int lane = tid & 63;
    const int m    = lane & 15;
    const int quad = lane >> 4;
    const int rowBase = blockIdx.x * BM + wave * 32;

    int code[2];
#pragma unroll
    for (int t = 0; t < 2; ++t) {
        const int row = rowBase + t * 16 + m;
        int day, tod;
        if (is64) { int4 te = *(const int4*)(TE32 + 4 * row); day = te.x; tod = te.z; }
        else      { int2 te = *(const int2*)(TE32 + 2 * row); day = te.x; tod = te.y; }
        int dm = day % 7; if (dm < 0) dm += 7;
        int tm = tod % T; if (tm < 0) tm += T;
        code[t] = dm * T + tm;
    }
    bf16x8 hfrag[2][8];
#pragma unroll
    for (int t = 0; t < 2; ++t)
#pragma unroll
        for (int ks = 0; ks < 8; ++ks)
            hfrag[t][ks] = *(const bf16x8*)(Htab + code[t] * 256 + ks * 32 + quad * 8);

    const bf16x8* __restrict__ gsrc = (const bf16x8*)W2S + tid;
    bf16x8* __restrict__ ldst = (bf16x8*)Bs + tid;
    const bf16x8* __restrict__ lsrc = (const bf16x8*)Bs;

    bf16x8 stage[8];
#pragma unroll
    for (int q = 0; q < 8; ++q) stage[q] = gsrc[q * 256];

    for (int g = 0; g < 4; ++g) {
#pragma unroll
        for (int q = 0; q < 8; ++q) ldst[q * 256] = stage[q];
        __syncthreads();
        if (g < 3) {
#pragma unroll
            for (int q = 0; q < 8; ++q) stage[q] = gsrc[(g + 1) * 2048 + q * 256];
        }
#pragma unroll
        for (int ntl = 0; ntl < 4; ++ntl) {
            const int nt = g * 4 + ntl;
            f32x4 acc0 = {0.f, 0.f, 0.f, 0.f};
            f32x4 acc1 = {0.f, 0.f, 0.f, 0.f};
#pragma unroll
            for (int ks = 0; ks < 8; ++ks) {
                bf16x8 wfrag = lsrc[(ntl * 8 + ks) * 64 + lane];
                acc0 = __builtin_amdgcn_mfma_f32_16x16x32_bf16(wfrag, hfrag[0][ks], acc0, 0, 0, 0);
                acc1 = __builtin_amdgcn_mfma_f32_16x16x32_bf16(wfrag, hfrag[1][ks], acc1, 0, 0, 0);
            }
            const f32x4 bias = *(const f32x4*)(b2 + nt * 16 + quad * 4);
            f32x4 v0, v1;
#pragma unroll
            for (int r = 0; r < 4; ++r) { v0[r] = acc0[r] + bias[r]; v1[r] = acc1[r] + bias[r]; }
            float* p0 = out + (rowBase + m) * 256 + nt * 16 + quad * 4;
            *(f32x4*)p0 = v0;
            *(f32x4*)(p0 + 16 * 256) = v1;
        }
        __syncthreads();
    }
}

extern "C" void kernel_launch(void* const* d_in, const int* in_sizes, int n_in,
                              void* d_out, int out_size, void* d_ws, size_t ws_size,
                              hipStream_t stream) {
    const int*   TE = (const int*)  d_in[0];   // [B,S,2] integer words
    const float* W1 = (const float*)d_in[2];   // [7+T,256]
    const float* b1 = (const float*)d_in[3];   // [256]
    const float* W2 = (const float*)d_in[4];   // [256,256]
    const float* b2 = (const float*)d_in[5];   // [256]
    const int T = in_sizes[2] / 256 - 7;       // 288

    const int otab_blocks = (7 * T + BM - 1) / BM;        // 16 for T=288
    const int otab_rows   = otab_blocks * BM;             // 2048

    const size_t hoff = 131072;                           // Htab
    const size_t foff = hoff + (size_t)7 * T * 512;       // flag (R0-compatible)
    const size_t ooff = foff + 256;                       // Otab, 16B-aligned
    const size_t need = ooff + (size_t)otab_rows * 1024;

    __bf16* W2S  = (__bf16*)d_ws;
    __bf16* Htab = (__bf16*)((char*)d_ws + hoff);
    int*    flag = (int*)  ((char*)d_ws + foff);
    float*  Otab = (float*)((char*)d_ws + ooff);
    float*  out  = (float*)d_out;

    prep_all<<<7 * T + 64, 64, 0, stream>>>(W1, b1, W2, W2S, Htab, TE, flag, T);
    if (ws_size >= need) {
        otab_gemm<<<otab_blocks, 256, 0, stream>>>(Htab, W2S, b2, Otab, T);
        gather_out<<<M_TOTAL / 64, 256, 0, stream>>>(TE, Otab, flag, out, T);
    } else {
        temb_gemm<<<M_TOTAL / BM, 256, 0, stream>>>(TE, Htab, W2S, b2, flag, out, T);
    }
}